// Round 2
// baseline (102.589 us; speedup 1.0000x reference)
//
#include <hip/hip_runtime.h>
#include <hip/hip_bf16.h>

// Problem constants (fixed by reference): B=4, C=64, H=W=64, N=4096
#define BATCH 4
#define NSP   4096

// (1/64)*sqrt(log2 e): both Q and K carry this, so S^T = score*log2e/4096 and
// softmax uses raw v_exp_f32 (2^x) with no per-element multiply.
#define QKSCALE 0.0187675376f

typedef __bf16 bf16x8v __attribute__((ext_vector_type(8)));
typedef __bf16 bf16x4v __attribute__((ext_vector_type(4)));
typedef float  floatx4 __attribute__((ext_vector_type(4)));
typedef float  floatx16 __attribute__((ext_vector_type(16)));
typedef unsigned uivec2 __attribute__((ext_vector_type(2)));

static __device__ __forceinline__ float fast_exp2(float x) {
#if __has_builtin(__builtin_amdgcn_exp2f)
    return __builtin_amdgcn_exp2f(x);
#else
    return exp2f(x);
#endif
}

// pack two f32 -> one dword of 2 bf16 (compiler emits v_cvt_pk_bf16_f32)
static __device__ __forceinline__ unsigned pkbf(float a, float b) {
    union { __bf16 h[2]; unsigned u; } x;
    x.h[0] = (__bf16)a; x.h[1] = (__bf16)b;
    return x.u;
}

// v_permlane32_swap_b32: a'[32:63] <- b[0:31], b'[0:31] <- a[32:63].
// Converts S^T D-layout (4-row groups per half) into PV B-layout (8-row
// groups per half): one swap yields TWO usable B-frag words (T12 recipe).
static __device__ __forceinline__ void plswap(unsigned &a, unsigned &b) {
#if __has_builtin(__builtin_amdgcn_permlane32_swap)
    uivec2 r = __builtin_amdgcn_permlane32_swap(a, b, false, false);
    a = r[0]; b = r[1];
#else
    asm("v_permlane32_swap_b32 %0, %1" : "+v"(a), "+v"(b));
#endif
}

// ---------------------------------------------------------------------------
// Kernel 1: qkT[b][n][o] = bf16( (sum_c W[o][c]*x[b][c][n] + bias[o]) * s ),
// s = QKSCALE (exp2 folding). Also emits xbf = bf16(x) so the attention
// kernel's V staging is a pure uint4 copy (half the bytes, zero cvt VALU).
// ---------------------------------------------------------------------------
__global__ __launch_bounds__(256) void qk_kernel(const float* __restrict__ x,
                                                 const float* __restrict__ Wm,
                                                 const float* __restrict__ bias,
                                                 __bf16* __restrict__ qkT,
                                                 __bf16* __restrict__ xbf) {
    __shared__ __align__(16) __bf16 xT[64 * 72];   // [n][c]; reused as [n][o] out buf

    const int t  = threadIdx.x;
    const int b  = blockIdx.x >> 6;
    const int n0 = (blockIdx.x & 63) << 6;

    // stage x^T tile, pre-scaled, coalesced float4 reads; also write bf16 V copy
#pragma unroll
    for (int p = 0; p < 4; ++p) {
        const int c  = p * 16 + (t >> 4);
        const int n4 = (t & 15) * 4;
        const float4 v = *(const float4*)(x + (size_t)(b * 64 + c) * 4096 + n0 + n4);
        xT[(n4 + 0) * 72 + c] = (__bf16)(v.x * QKSCALE);
        xT[(n4 + 1) * 72 + c] = (__bf16)(v.y * QKSCALE);
        xT[(n4 + 2) * 72 + c] = (__bf16)(v.z * QKSCALE);
        xT[(n4 + 3) * 72 + c] = (__bf16)(v.w * QKSCALE);
        bf16x4v xv;
        xv[0] = (__bf16)v.x; xv[1] = (__bf16)v.y; xv[2] = (__bf16)v.z; xv[3] = (__bf16)v.w;
        *(bf16x4v*)(xbf + (size_t)(b * 64 + c) * 4096 + n0 + n4) = xv;
    }
    __syncthreads();

    const int w = t >> 6, lane = t & 63, quad = lane >> 4, l16 = lane & 15;
    // A-frags: A[n=l16][c=quad*8+j], wave w owns n-rows w*16..+15
    const bf16x8v a0 = *(const bf16x8v*)(xT + (w * 16 + l16) * 72 + quad * 8);
    const bf16x8v a1 = *(const bf16x8v*)(xT + (w * 16 + l16) * 72 + 32 + quad * 8);

    floatx4 acc[4];
#pragma unroll
    for (int ot = 0; ot < 4; ++ot) {
        // B-frags straight from global W (fp32 -> bf16): B[k=c][n=o], o=ot*16+l16
        const float* wr = Wm + (ot * 16 + l16) * 64;
        float4 wa = *(const float4*)(wr + quad * 8);
        float4 wb = *(const float4*)(wr + quad * 8 + 4);
        float4 wc = *(const float4*)(wr + 32 + quad * 8);
        float4 wd = *(const float4*)(wr + 32 + quad * 8 + 4);
        bf16x8v b0, b1;
        b0[0]=(__bf16)wa.x; b0[1]=(__bf16)wa.y; b0[2]=(__bf16)wa.z; b0[3]=(__bf16)wa.w;
        b0[4]=(__bf16)wb.x; b0[5]=(__bf16)wb.y; b0[6]=(__bf16)wb.z; b0[7]=(__bf16)wb.w;
        b1[0]=(__bf16)wc.x; b1[1]=(__bf16)wc.y; b1[2]=(__bf16)wc.z; b1[3]=(__bf16)wc.w;
        b1[4]=(__bf16)wd.x; b1[5]=(__bf16)wd.y; b1[6]=(__bf16)wd.z; b1[7]=(__bf16)wd.w;
        acc[ot] = floatx4{0.f, 0.f, 0.f, 0.f};
        acc[ot] = __builtin_amdgcn_mfma_f32_16x16x32_bf16(a0, b0, acc[ot], 0, 0, 0);
        acc[ot] = __builtin_amdgcn_mfma_f32_16x16x32_bf16(a1, b1, acc[ot], 0, 0, 0);
    }
    __syncthreads();   // all xT frag reads done before reuse as [n][o]

    // D: row(quad*4+r)=n_local within wave's 16-n, col(l16)=o_local
#pragma unroll
    for (int ot = 0; ot < 4; ++ot) {
        const float bo = bias[ot * 16 + l16] * QKSCALE;
#pragma unroll
        for (int r = 0; r < 4; ++r)
            xT[(w * 16 + quad * 4 + r) * 72 + ot * 16 + l16] = (__bf16)(acc[ot][r] + bo);
    }
    __syncthreads();

    const int n = t >> 2, seg = t & 3;
    __bf16* dst = qkT + (size_t)(b * 4096 + n0 + n) * 64 + seg * 16;
    *(bf16x8v*)dst       = *(const bf16x8v*)(xT + n * 72 + seg * 16);
    *(bf16x8v*)(dst + 8) = *(const bf16x8v*)(xT + n * 72 + seg * 16 + 8);
}

// ---------------------------------------------------------------------------
// Kernel 2: flash-style attention, 32x32 MFMA restructure.
//  * Block = (b, 256-q tile, m-chunk); 4 waves, each owning 64 q.
//  * QK^T: S^T = K.Q^T via mfma_32x32x16; K and Q frags read straight from
//    global (qkT is 2 MB, L2-resident) -- no K LDS traffic at all.
//  * P stays in registers: cvt_pk pairs + v_permlane32_swap_b32 convert the
//    S^T D-layout into the PV B-operand layout (2 swaps per 16-k block).
//  * Only V staged in LDS (bf16, double-buffered, XOR slot swizzle
//    slot = col8 ^ (c&7) -> bank-uniform b128 reads and writes).
//  * exp2 (scale folded into qkT by kernel 1).
// LDS: V dbuf 16 KB; epilogue Olds [64][260] f32 aliases (65 KB) -> 2 blk/CU.
// ---------------------------------------------------------------------------
template<int SPLIT, int ITERS>
__global__ __launch_bounds__(256, 2) void attn_kernel(const __bf16* __restrict__ xbf,
                                                      const __bf16* __restrict__ qkT,
                                                      __bf16* __restrict__ Opart,
                                                      float* __restrict__ Lpart) {
    __shared__ __align__(16) char smem[66560];
    __bf16* Vlds = (__bf16*)smem;                 // [2][64 c][64 m] swizzled
    float*  Olds = (float*)smem;                  // epilogue alias: [64 c][260 q]

    const int t   = threadIdx.x;
    const int blk = blockIdx.x;
    const int xcd = blk & 7;                      // XCD round-robin
    const int b   = xcd >> 1;                     // each b pinned to 2 XCDs
    const int sub = ((blk >> 3) << 1) | (xcd & 1);
    const int qt  = sub / SPLIT;
    const int s   = sub % SPLIT;
    const int n0  = qt << 8;
    const int pblk = (b * 16 + qt) * SPLIT + s;

    const int w = t >> 6, lane = t & 63, l31 = lane & 31, hi = lane >> 5;

    const __bf16* kgl = qkT + (size_t)b * 4096 * 64;   // [n][c] bf16
    const __bf16* vgl = xbf + (size_t)b * 64 * 4096;   // [c][n] bf16

    // Q B-frags from global: B[k = kb*16 + hi*8 + j][q = w*64 + qt2*32 + l31]
    bf16x8v qf[2][4];
#pragma unroll
    for (int qt2 = 0; qt2 < 2; ++qt2) {
        const __bf16* qrow = kgl + (size_t)(n0 + w * 64 + qt2 * 32 + l31) * 64;
#pragma unroll
        for (int kb = 0; kb < 4; ++kb)
            qf[qt2][kb] = *(const bf16x8v*)(qrow + kb * 16 + hi * 8);
    }

    // oacc[qt2][ct]: 32x32 D tiles: col=q=l31, row c = ct*32+(r&3)+8*(r>>2)+4*hi
    floatx16 oacc[2][2] = {};
    float rs[2] = {0.f, 0.f};

    // V staging: 2 x uint4 per thread; swizzled slot within each 128B row
    const int c0    = t >> 3;                 // 0..31 (and +32)
    const int col8  = t & 7;
    const int slot0 = ((col8 ^ (c0 & 7)) * 8);
    uint4 vst0, vst1;
    auto stage_load = [&](int m0) {
        vst0 = *(const uint4*)(vgl + (size_t)c0 * 4096 + m0 + col8 * 8);
        vst1 = *(const uint4*)(vgl + (size_t)(c0 + 32) * 4096 + m0 + col8 * 8);
    };
    auto stage_write = [&](int buf) {
        __bf16* vd = Vlds + buf * 4096;
        *(uint4*)(vd + c0 * 64 + slot0)        = vst0;
        *(uint4*)(vd + (c0 + 32) * 64 + slot0) = vst1;
    };

    const int mbase = s * (64 * ITERS);
    stage_load(mbase);
    stage_write(0);
    int cur = 0;

    for (int it = 0; it < ITERS; ++it) {
        const int m0 = mbase + (it << 6);
        if (it + 1 < ITERS) stage_load(m0 + 64);   // prefetch next V tile -> regs
        __syncthreads();                           // cur buffer visible
        const __bf16* Vc = Vlds + cur * 4096;

#pragma unroll
        for (int mt = 0; mt < 2; ++mt) {
            // K A-frags from global: A[m = mt*32 + l31][c = kb*16 + hi*8 + j]
            bf16x8v kf[4];
#pragma unroll
            for (int kb = 0; kb < 4; ++kb)
                kf[kb] = *(const bf16x8v*)(kgl + (size_t)(m0 + mt * 32 + l31) * 64 + kb * 16 + hi * 8);

            // V A-frags (shared across qt2): A[c = ct*32 + l31][m'= ks*16 + hi*8 + j]
            bf16x8v vf[2][2];
#pragma unroll
            for (int ct = 0; ct < 2; ++ct)
#pragma unroll
                for (int ks = 0; ks < 2; ++ks) {
                    const int c  = ct * 32 + l31;
                    const int sl = ((mt * 4 + ks * 2 + hi) ^ (c & 7)) * 8;
                    vf[ct][ks] = *(const bf16x8v*)(Vc + c * 64 + sl);
                }

#pragma unroll
            for (int qt2 = 0; qt2 < 2; ++qt2) {
                floatx16 acc = {};
#pragma unroll
                for (int kb = 0; kb < 4; ++kb)
                    acc = __builtin_amdgcn_mfma_f32_32x32x16_bf16(kf[kb], qf[qt2][kb], acc, 0, 0, 0);

                // softmax numerator: p = 2^sT (rows m' = (r&3)+8*(r>>2)+4*hi)
                float p[16];
                float sum = 0.f;
#pragma unroll
                for (int i = 0; i < 16; ++i) { p[i] = fast_exp2(acc[i]); sum += p[i]; }
                rs[qt2] += sum;

                // pack row-pairs, swap halves -> PV B-frags (k = hi*8 + j)
                unsigned wd0 = pkbf(p[0],  p[1]),  wd1 = pkbf(p[2],  p[3]);
                unsigned wd2 = pkbf(p[4],  p[5]),  wd3 = pkbf(p[6],  p[7]);
                unsigned wd4 = pkbf(p[8],  p[9]),  wd5 = pkbf(p[10], p[11]);
                unsigned wd6 = pkbf(p[12], p[13]), wd7 = pkbf(p[14], p[15]);
                plswap(wd0, wd2);   // wd0 = word0 (k 0,1 | 8,9), wd2 = word2
                plswap(wd1, wd3);   // wd1 = word1,               wd3 = word3
                plswap(wd4, wd6);   // ks=1 block (m'+16)
                plswap(wd5, wd7);
                union { unsigned u[4]; bf16x8v v; } pb0, pb1;
                pb0.u[0] = wd0; pb0.u[1] = wd1; pb0.u[2] = wd2; pb0.u[3] = wd3;
                pb1.u[0] = wd4; pb1.u[1] = wd5; pb1.u[2] = wd6; pb1.u[3] = wd7;

                // O[c][q] += V[c][m'] * P[m'][q]
#pragma unroll
                for (int ct = 0; ct < 2; ++ct) {
                    oacc[qt2][ct] = __builtin_amdgcn_mfma_f32_32x32x16_bf16(vf[ct][0], pb0.v, oacc[qt2][ct], 0, 0, 0);
                    oacc[qt2][ct] = __builtin_amdgcn_mfma_f32_32x32x16_bf16(vf[ct][1], pb1.v, oacc[qt2][ct], 0, 0, 0);
                }
            }
        }

        if (it + 1 < ITERS) stage_write(cur ^ 1);  // vmcnt wait lands here (hidden)
        cur ^= 1;
    }

    // row-sums: each (q, hi) holds a half-sum; combine across halves
#pragma unroll
    for (int qt2 = 0; qt2 < 2; ++qt2) {
        float v = rs[qt2] + __shfl_xor(rs[qt2], 32, 64);
        if (lane < 32)
            Lpart[(size_t)pblk * 256 + w * 64 + qt2 * 32 + l31] = v;
    }

    __syncthreads();   // all V LDS reads done before reuse as Olds

    // transpose via LDS: Olds[c][q], then packed bf16 stores
#pragma unroll
    for (int qt2 = 0; qt2 < 2; ++qt2)
#pragma unroll
        for (int ct = 0; ct < 2; ++ct)
#pragma unroll
            for (int r = 0; r < 16; ++r) {
                const int c = ct * 32 + (r & 3) + 8 * (r >> 2) + 4 * hi;
                Olds[c * 260 + w * 64 + qt2 * 32 + l31] = oacc[qt2][ct][r];
            }
    __syncthreads();

    const int c = t >> 2, qb = (t & 3) * 64;
#pragma unroll
    for (int i = 0; i < 8; ++i) {
        floatx4 v0 = *(const floatx4*)(Olds + c * 260 + qb + i * 8);
        floatx4 v1 = *(const floatx4*)(Olds + c * 260 + qb + i * 8 + 4);
        bf16x8v pk;
        pk[0]=(__bf16)v0[0]; pk[1]=(__bf16)v0[1]; pk[2]=(__bf16)v0[2]; pk[3]=(__bf16)v0[3];
        pk[4]=(__bf16)v1[0]; pk[5]=(__bf16)v1[1]; pk[6]=(__bf16)v1[2]; pk[7]=(__bf16)v1[3];
        *(bf16x8v*)(Opart + (size_t)pblk * 16384 + c * 256 + qb + i * 8) = pk;
    }
}

// ---------------------------------------------------------------------------
// Kernel 3: combine SPLIT m-chunk partials, normalize, store fp32 output.
// 512 blocks x 256 thr; 16B Opart loads, 8-deep MLP.
// ---------------------------------------------------------------------------
template<int SPLIT>
__global__ __launch_bounds__(256) void reduce_kernel(const __bf16* __restrict__ Opart,
                                                     const float* __restrict__ Lpart,
                                                     float* __restrict__ out) {
    const int blk = blockIdx.x;            // bq(64) x cq(8)
    const int bq = blk >> 3, cq = blk & 7;
    const int b = bq >> 4, qt = bq & 15;
    const int t = threadIdx.x;
    const int c  = cq * 8 + (t >> 5);      // channel
    const int q8 = (t & 31) * 8;           // q offset (8 per thread)

    float l[8] = {0.f,0.f,0.f,0.f,0.f,0.f,0.f,0.f};
#pragma unroll
    for (int s = 0; s < SPLIT; ++s) {
        const float* lp = Lpart + ((size_t)bq * SPLIT + s) * 256 + q8;
        float4 u = *(const float4*)lp;
        float4 v = *(const float4*)(lp + 4);
        l[0]+=u.x; l[1]+=u.y; l[2]+=u.z; l[3]+=u.w;
        l[4]+=v.x; l[5]+=v.y; l[6]+=v.z; l[7]+=v.w;
    }
    float a[8] = {0.f,0.f,0.f,0.f,0.f,0.f,0.f,0.f};
#pragma unroll
    for (int s = 0; s < SPLIT; ++s) {
        bf16x8v v = *(const bf16x8v*)(Opart + ((size_t)bq * SPLIT + s) * 16384 + c * 256 + q8);
#pragma unroll
        for (int k = 0; k < 8; ++k) a[k] += (float)v[k];
    }
    float* op = out + (size_t)(b * 64 + c) * 4096 + qt * 256 + q8;
    float4 o0, o1;
    o0.x = a[0]/l[0]; o0.y = a[1]/l[1]; o0.z = a[2]/l[2]; o0.w = a[3]/l[3];
    o1.x = a[4]/l[4]; o1.y = a[5]/l[5]; o1.z = a[6]/l[6]; o1.w = a[7]/l[7];
    *(float4*)op       = o0;
    *(float4*)(op + 4) = o1;
}

// ---------------------------------------------------------------------------
extern "C" void kernel_launch(void* const* d_in, const int* in_sizes, int n_in,
                              void* d_out, int out_size, void* d_ws, size_t ws_size,
                              hipStream_t stream) {
    const float* x    = (const float*)d_in[0];   // [4][64][4096]
    const float* Wm   = (const float*)d_in[1];   // [64][64]
    const float* bias = (const float*)d_in[2];   // [64]
    float* out = (float*)d_out;                  // [4][64][4096]

    char* ws = (char*)d_ws;
    __bf16* qkT = (__bf16*)ws;                   // 2 MB [4][4096][64] bf16
    __bf16* xbf = (__bf16*)(ws + 2097152);       // 2 MB [4][64][4096] bf16

    qk_kernel<<<BATCH * (NSP / 64), 256, 0, stream>>>(x, Wm, bias, qkT, xbf);

    const size_t HEAD = 2097152 + 2097152;
    const size_t needBig = HEAD + (size_t)512 * 16384 * 2 + (size_t)512 * 256 * 4;  // ~21 MB
    if (ws_size >= needBig) {
        __bf16* Opart = (__bf16*)(ws + HEAD);                           // 16 MB [512][64][256]
        float*  Lpart = (float*)(ws + HEAD + (size_t)512 * 16384 * 2);  // 512 KB
        attn_kernel<8, 8><<<BATCH * 16 * 8, 256, 0, stream>>>(xbf, qkT, Opart, Lpart);
        reduce_kernel<8><<<512, 256, 0, stream>>>(Opart, Lpart, out);
    } else {
        __bf16* Opart = (__bf16*)(ws + HEAD);                           // 8 MB [256][64][256]
        float*  Lpart = (float*)(ws + HEAD + (size_t)256 * 16384 * 2);  // 256 KB
        attn_kernel<4, 16><<<BATCH * 16 * 4, 256, 0, stream>>>(xbf, qkT, Opart, Lpart);
        reduce_kernel<4><<<512, 256, 0, stream>>>(Opart, Lpart, out);
    }
}

// Round 3
// 98.367 us; speedup vs baseline: 1.0429x; 1.0429x over previous
//
#include <hip/hip_runtime.h>
#include <hip/hip_bf16.h>

// Problem constants (fixed by reference): B=4, C=64, H=W=64, N=4096
#define BATCH 4
#define NSP   4096

// (1/64)*sqrt(log2 e): both Q and K carry this, so S^T = score*log2e/4096 and
// softmax uses raw v_exp_f32 (2^x) with no per-element multiply.
#define QKSCALE 0.0187675376f

typedef __bf16 bf16x8v __attribute__((ext_vector_type(8)));
typedef __bf16 bf16x4v __attribute__((ext_vector_type(4)));
typedef float  floatx4 __attribute__((ext_vector_type(4)));
typedef float  floatx16 __attribute__((ext_vector_type(16)));
typedef unsigned uivec2 __attribute__((ext_vector_type(2)));

static __device__ __forceinline__ float fast_exp2(float x) {
#if __has_builtin(__builtin_amdgcn_exp2f)
    return __builtin_amdgcn_exp2f(x);
#else
    return exp2f(x);
#endif
}

// pack two f32 -> one dword of 2 bf16 (compiler emits v_cvt_pk_bf16_f32)
static __device__ __forceinline__ unsigned pkbf(float a, float b) {
    union { __bf16 h[2]; unsigned u; } x;
    x.h[0] = (__bf16)a; x.h[1] = (__bf16)b;
    return x.u;
}

// v_permlane32_swap_b32: a'[32:63] <- b[0:31], b'[0:31] <- a[32:63].
// Converts S^T D-layout (4-row groups per half) into PV B-layout (8-row
// groups per half): one swap yields TWO usable B-frag words (T12 recipe).
// Verified on HW in R2 (bit-identical absmax vs 16x16 version).
static __device__ __forceinline__ void plswap(unsigned &a, unsigned &b) {
#if __has_builtin(__builtin_amdgcn_permlane32_swap)
    uivec2 r = __builtin_amdgcn_permlane32_swap(a, b, false, false);
    a = r[0]; b = r[1];
#else
    asm("v_permlane32_swap_b32 %0, %1" : "+v"(a), "+v"(b));
#endif
}

// ---------------------------------------------------------------------------
// Kernel 1: qkT[b][n][o] = bf16( (sum_c W[o][c]*x[b][c][n] + bias[o]) * s ),
// s = QKSCALE (exp2 folding). Also emits xbf = bf16(x) so the attention
// kernel's V staging is a pure uint4 copy (half the bytes, zero cvt VALU).
// ---------------------------------------------------------------------------
__global__ __launch_bounds__(256) void qk_kernel(const float* __restrict__ x,
                                                 const float* __restrict__ Wm,
                                                 const float* __restrict__ bias,
                                                 __bf16* __restrict__ qkT,
                                                 __bf16* __restrict__ xbf) {
    __shared__ __align__(16) __bf16 xT[64 * 72];   // [n][c]; reused as [n][o] out buf

    const int t  = threadIdx.x;
    const int b  = blockIdx.x >> 6;
    const int n0 = (blockIdx.x & 63) << 6;

    // stage x^T tile, pre-scaled, coalesced float4 reads; also write bf16 V copy
#pragma unroll
    for (int p = 0; p < 4; ++p) {
        const int c  = p * 16 + (t >> 4);
        const int n4 = (t & 15) * 4;
        const float4 v = *(const float4*)(x + (size_t)(b * 64 + c) * 4096 + n0 + n4);
        xT[(n4 + 0) * 72 + c] = (__bf16)(v.x * QKSCALE);
        xT[(n4 + 1) * 72 + c] = (__bf16)(v.y * QKSCALE);
        xT[(n4 + 2) * 72 + c] = (__bf16)(v.z * QKSCALE);
        xT[(n4 + 3) * 72 + c] = (__bf16)(v.w * QKSCALE);
        bf16x4v xv;
        xv[0] = (__bf16)v.x; xv[1] = (__bf16)v.y; xv[2] = (__bf16)v.z; xv[3] = (__bf16)v.w;
        *(bf16x4v*)(xbf + (size_t)(b * 64 + c) * 4096 + n0 + n4) = xv;
    }
    __syncthreads();

    const int w = t >> 6, lane = t & 63, quad = lane >> 4, l16 = lane & 15;
    // A-frags: A[n=l16][c=quad*8+j], wave w owns n-rows w*16..+15
    const bf16x8v a0 = *(const bf16x8v*)(xT + (w * 16 + l16) * 72 + quad * 8);
    const bf16x8v a1 = *(const bf16x8v*)(xT + (w * 16 + l16) * 72 + 32 + quad * 8);

    floatx4 acc[4];
#pragma unroll
    for (int ot = 0; ot < 4; ++ot) {
        // B-frags straight from global W (fp32 -> bf16): B[k=c][n=o], o=ot*16+l16
        const float* wr = Wm + (ot * 16 + l16) * 64;
        float4 wa = *(const float4*)(wr + quad * 8);
        float4 wb = *(const float4*)(wr + quad * 8 + 4);
        float4 wc = *(const float4*)(wr + 32 + quad * 8);
        float4 wd = *(const float4*)(wr + 32 + quad * 8 + 4);
        bf16x8v b0, b1;
        b0[0]=(__bf16)wa.x; b0[1]=(__bf16)wa.y; b0[2]=(__bf16)wa.z; b0[3]=(__bf16)wa.w;
        b0[4]=(__bf16)wb.x; b0[5]=(__bf16)wb.y; b0[6]=(__bf16)wb.z; b0[7]=(__bf16)wb.w;
        b1[0]=(__bf16)wc.x; b1[1]=(__bf16)wc.y; b1[2]=(__bf16)wc.z; b1[3]=(__bf16)wc.w;
        b1[4]=(__bf16)wd.x; b1[5]=(__bf16)wd.y; b1[6]=(__bf16)wd.z; b1[7]=(__bf16)wd.w;
        acc[ot] = floatx4{0.f, 0.f, 0.f, 0.f};
        acc[ot] = __builtin_amdgcn_mfma_f32_16x16x32_bf16(a0, b0, acc[ot], 0, 0, 0);
        acc[ot] = __builtin_amdgcn_mfma_f32_16x16x32_bf16(a1, b1, acc[ot], 0, 0, 0);
    }
    __syncthreads();   // all xT frag reads done before reuse as [n][o]

    // D: row(quad*4+r)=n_local within wave's 16-n, col(l16)=o_local
#pragma unroll
    for (int ot = 0; ot < 4; ++ot) {
        const float bo = bias[ot * 16 + l16] * QKSCALE;
#pragma unroll
        for (int r = 0; r < 4; ++r)
            xT[(w * 16 + quad * 4 + r) * 72 + ot * 16 + l16] = (__bf16)(acc[ot][r] + bo);
    }
    __syncthreads();

    const int n = t >> 2, seg = t & 3;
    __bf16* dst = qkT + (size_t)(b * 4096 + n0 + n) * 64 + seg * 16;
    *(bf16x8v*)dst       = *(const bf16x8v*)(xT + n * 72 + seg * 16);
    *(bf16x8v*)(dst + 8) = *(const bf16x8v*)(xT + n * 72 + seg * 16 + 8);
}

// ---------------------------------------------------------------------------
// Kernel 2: flash-style attention, 32x32 MFMA. R3 change vs R2: K staged in
// LDS exactly like V (XOR-swizzled, double-buffered) instead of per-mt global
// reads -- R2's +5us regression was the un-hidden L2 latency + 4x re-read
// amplification of the global-K path.
//  * Block = (b, 256-q tile, m-chunk); 4 waves, each owning 64 q.
//  * QK^T: S^T = K.Q^T via mfma_32x32x16; P stays in registers via
//    cvt_pk + v_permlane32_swap_b32 (verified R2); PV at full 32x32 rate.
//  * One barrier per iter; global->reg prefetch before barrier, LDS write
//    after compute (T14); s_setprio around the MFMA/compute cluster (T5).
// LDS: K dbuf 16KB + V dbuf 16KB = 32KB; epilogue Olds [64][260] f32 alias
// (65KB) -> 2 blocks/CU (grid-limited to 2 anyway).
// ---------------------------------------------------------------------------
template<int SPLIT, int ITERS>
__global__ __launch_bounds__(256, 2) void attn_kernel(const __bf16* __restrict__ xbf,
                                                      const __bf16* __restrict__ qkT,
                                                      __bf16* __restrict__ Opart,
                                                      float* __restrict__ Lpart) {
    __shared__ __align__(16) char smem[66560];
    __bf16* Klds = (__bf16*)smem;                 // [2][64 m][64 c] swizzled
    __bf16* Vlds = (__bf16*)(smem + 16384);       // [2][64 c][64 m] swizzled
    float*  Olds = (float*)smem;                  // epilogue alias: [64 c][260 q]

    const int t   = threadIdx.x;
    const int blk = blockIdx.x;
    const int xcd = blk & 7;                      // XCD round-robin
    const int b   = xcd >> 1;                     // each b pinned to 2 XCDs
    const int sub = ((blk >> 3) << 1) | (xcd & 1);
    const int qt  = sub / SPLIT;
    const int s   = sub % SPLIT;
    const int n0  = qt << 8;
    const int pblk = (b * 16 + qt) * SPLIT + s;

    const int w = t >> 6, lane = t & 63, l31 = lane & 31, hi = lane >> 5;

    const __bf16* kgl = qkT + (size_t)b * 4096 * 64;   // [n][c] bf16
    const __bf16* vgl = xbf + (size_t)b * 64 * 4096;   // [c][n] bf16

    // Q B-frags from global: B[k = kb*16 + hi*8 + j][q = w*64 + qt2*32 + l31]
    bf16x8v qf[2][4];
#pragma unroll
    for (int qt2 = 0; qt2 < 2; ++qt2) {
        const __bf16* qrow = kgl + (size_t)(n0 + w * 64 + qt2 * 32 + l31) * 64;
#pragma unroll
        for (int kb = 0; kb < 4; ++kb)
            qf[qt2][kb] = *(const bf16x8v*)(qrow + kb * 16 + hi * 8);
    }

    // oacc[qt2][ct]: 32x32 D tiles: col=q=l31, row c = ct*32+(r&3)+8*(r>>2)+4*hi
    floatx16 oacc[2][2] = {};
    float rs[2] = {0.f, 0.f};

    // staging: 2 K-granules + 2 V-granules per thread (16B each), XOR slot
    const int srow = t >> 3;                  // 0..31 (and +32)
    const int scol = t & 7;
    const int slot = ((scol ^ (srow & 7)) * 8);
    uint4 kst0, kst1, vst0, vst1;
    auto stage_load = [&](int m0) {
        kst0 = *(const uint4*)(kgl + (size_t)(m0 + srow) * 64 + scol * 8);
        kst1 = *(const uint4*)(kgl + (size_t)(m0 + srow + 32) * 64 + scol * 8);
        vst0 = *(const uint4*)(vgl + (size_t)srow * 4096 + m0 + scol * 8);
        vst1 = *(const uint4*)(vgl + (size_t)(srow + 32) * 4096 + m0 + scol * 8);
    };
    auto stage_write = [&](int buf) {
        __bf16* kd = Klds + buf * 4096;
        __bf16* vd = Vlds + buf * 4096;
        *(uint4*)(kd + srow * 64 + slot)        = kst0;
        *(uint4*)(kd + (srow + 32) * 64 + slot) = kst1;
        *(uint4*)(vd + srow * 64 + slot)        = vst0;
        *(uint4*)(vd + (srow + 32) * 64 + slot) = vst1;
    };

    const int mbase = s * (64 * ITERS);
    stage_load(mbase);
    stage_write(0);
    int cur = 0;

    for (int it = 0; it < ITERS; ++it) {
        if (it + 1 < ITERS) stage_load(mbase + ((it + 1) << 6));  // prefetch -> regs
        __syncthreads();                                          // cur buffers visible
        const __bf16* Kc = Klds + cur * 4096;
        const __bf16* Vc = Vlds + cur * 4096;

        __builtin_amdgcn_s_setprio(1);
#pragma unroll
        for (int mt = 0; mt < 2; ++mt) {
            // K A-frags from LDS: A[m = mt*32 + l31][c = kb*16 + hi*8 + j]
            // stored slot for col8'=(kb*2+hi) is (col8' ^ (m&7))*8
            bf16x8v kf[4];
#pragma unroll
            for (int kb = 0; kb < 4; ++kb)
                kf[kb] = *(const bf16x8v*)(Kc + (mt * 32 + l31) * 64 +
                                           (((kb * 2 + hi) ^ (l31 & 7)) * 8));

            // V A-frags (shared across qt2): A[c = ct*32 + l31][m'= ks*16 + hi*8 + j]
            bf16x8v vf[2][2];
#pragma unroll
            for (int ct = 0; ct < 2; ++ct)
#pragma unroll
                for (int ks = 0; ks < 2; ++ks)
                    vf[ct][ks] = *(const bf16x8v*)(Vc + (ct * 32 + l31) * 64 +
                                                   (((mt * 4 + ks * 2 + hi) ^ (l31 & 7)) * 8));

#pragma unroll
            for (int qt2 = 0; qt2 < 2; ++qt2) {
                floatx16 acc = {};
#pragma unroll
                for (int kb = 0; kb < 4; ++kb)
                    acc = __builtin_amdgcn_mfma_f32_32x32x16_bf16(kf[kb], qf[qt2][kb], acc, 0, 0, 0);

                // softmax numerator: p = 2^sT (rows m' = (r&3)+8*(r>>2)+4*hi)
                float p[16];
                float sum = 0.f;
#pragma unroll
                for (int i = 0; i < 16; ++i) { p[i] = fast_exp2(acc[i]); sum += p[i]; }
                rs[qt2] += sum;

                // pack row-pairs, swap halves -> PV B-frags (k = hi*8 + j)
                unsigned wd0 = pkbf(p[0],  p[1]),  wd1 = pkbf(p[2],  p[3]);
                unsigned wd2 = pkbf(p[4],  p[5]),  wd3 = pkbf(p[6],  p[7]);
                unsigned wd4 = pkbf(p[8],  p[9]),  wd5 = pkbf(p[10], p[11]);
                unsigned wd6 = pkbf(p[12], p[13]), wd7 = pkbf(p[14], p[15]);
                plswap(wd0, wd2);   // wd0 = word0 (k 0,1 | 8,9), wd2 = word2
                plswap(wd1, wd3);   // wd1 = word1,               wd3 = word3
                plswap(wd4, wd6);   // ks=1 block (m'+16)
                plswap(wd5, wd7);
                union { unsigned u[4]; bf16x8v v; } pb0, pb1;
                pb0.u[0] = wd0; pb0.u[1] = wd1; pb0.u[2] = wd2; pb0.u[3] = wd3;
                pb1.u[0] = wd4; pb1.u[1] = wd5; pb1.u[2] = wd6; pb1.u[3] = wd7;

                // O[c][q] += V[c][m'] * P[m'][q]
#pragma unroll
                for (int ct = 0; ct < 2; ++ct) {
                    oacc[qt2][ct] = __builtin_amdgcn_mfma_f32_32x32x16_bf16(vf[ct][0], pb0.v, oacc[qt2][ct], 0, 0, 0);
                    oacc[qt2][ct] = __builtin_amdgcn_mfma_f32_32x32x16_bf16(vf[ct][1], pb1.v, oacc[qt2][ct], 0, 0, 0);
                }
            }
        }
        __builtin_amdgcn_s_setprio(0);

        if (it + 1 < ITERS) stage_write(cur ^ 1);  // vmcnt wait lands here (hidden)
        cur ^= 1;
    }

    // row-sums: each (q, hi) holds a half-sum; combine across halves
#pragma unroll
    for (int qt2 = 0; qt2 < 2; ++qt2) {
        float v = rs[qt2] + __shfl_xor(rs[qt2], 32, 64);
        if (lane < 32)
            Lpart[(size_t)pblk * 256 + w * 64 + qt2 * 32 + l31] = v;
    }

    __syncthreads();   // all K/V LDS reads done before reuse as Olds

    // transpose via LDS: Olds[c][q], then packed bf16 stores
#pragma unroll
    for (int qt2 = 0; qt2 < 2; ++qt2)
#pragma unroll
        for (int ct = 0; ct < 2; ++ct)
#pragma unroll
            for (int r = 0; r < 16; ++r) {
                const int c = ct * 32 + (r & 3) + 8 * (r >> 2) + 4 * hi;
                Olds[c * 260 + w * 64 + qt2 * 32 + l31] = oacc[qt2][ct][r];
            }
    __syncthreads();

    const int c = t >> 2, qb = (t & 3) * 64;
#pragma unroll
    for (int i = 0; i < 8; ++i) {
        floatx4 v0 = *(const floatx4*)(Olds + c * 260 + qb + i * 8);
        floatx4 v1 = *(const floatx4*)(Olds + c * 260 + qb + i * 8 + 4);
        bf16x8v pk;
        pk[0]=(__bf16)v0[0]; pk[1]=(__bf16)v0[1]; pk[2]=(__bf16)v0[2]; pk[3]=(__bf16)v0[3];
        pk[4]=(__bf16)v1[0]; pk[5]=(__bf16)v1[1]; pk[6]=(__bf16)v1[2]; pk[7]=(__bf16)v1[3];
        *(bf16x8v*)(Opart + (size_t)pblk * 16384 + c * 256 + qb + i * 8) = pk;
    }
}

// ---------------------------------------------------------------------------
// Kernel 3: combine SPLIT m-chunk partials, normalize, store fp32 output.
// 512 blocks x 256 thr; 16B Opart loads, 8-deep MLP.
// ---------------------------------------------------------------------------
template<int SPLIT>
__global__ __launch_bounds__(256) void reduce_kernel(const __bf16* __restrict__ Opart,
                                                     const float* __restrict__ Lpart,
                                                     float* __restrict__ out) {
    const int blk = blockIdx.x;            // bq(64) x cq(8)
    const int bq = blk >> 3, cq = blk & 7;
    const int b = bq >> 4, qt = bq & 15;
    const int t = threadIdx.x;
    const int c  = cq * 8 + (t >> 5);      // channel
    const int q8 = (t & 31) * 8;           // q offset (8 per thread)

    float l[8] = {0.f,0.f,0.f,0.f,0.f,0.f,0.f,0.f};
#pragma unroll
    for (int s = 0; s < SPLIT; ++s) {
        const float* lp = Lpart + ((size_t)bq * SPLIT + s) * 256 + q8;
        float4 u = *(const float4*)lp;
        float4 v = *(const float4*)(lp + 4);
        l[0]+=u.x; l[1]+=u.y; l[2]+=u.z; l[3]+=u.w;
        l[4]+=v.x; l[5]+=v.y; l[6]+=v.z; l[7]+=v.w;
    }
    float a[8] = {0.f,0.f,0.f,0.f,0.f,0.f,0.f,0.f};
#pragma unroll
    for (int s = 0; s < SPLIT; ++s) {
        bf16x8v v = *(const bf16x8v*)(Opart + ((size_t)bq * SPLIT + s) * 16384 + c * 256 + q8);
#pragma unroll
        for (int k = 0; k < 8; ++k) a[k] += (float)v[k];
    }
    float* op = out + (size_t)(b * 64 + c) * 4096 + qt * 256 + q8;
    float4 o0, o1;
    o0.x = a[0]/l[0]; o0.y = a[1]/l[1]; o0.z = a[2]/l[2]; o0.w = a[3]/l[3];
    o1.x = a[4]/l[4]; o1.y = a[5]/l[5]; o1.z = a[6]/l[6]; o1.w = a[7]/l[7];
    *(float4*)op       = o0;
    *(float4*)(op + 4) = o1;
}

// ---------------------------------------------------------------------------
extern "C" void kernel_launch(void* const* d_in, const int* in_sizes, int n_in,
                              void* d_out, int out_size, void* d_ws, size_t ws_size,
                              hipStream_t stream) {
    const float* x    = (const float*)d_in[0];   // [4][64][4096]
    const float* Wm   = (const float*)d_in[1];   // [64][64]
    const float* bias = (const float*)d_in[2];   // [64]
    float* out = (float*)d_out;                  // [4][64][4096]

    char* ws = (char*)d_ws;
    __bf16* qkT = (__bf16*)ws;                   // 2 MB [4][4096][64] bf16
    __bf16* xbf = (__bf16*)(ws + 2097152);       // 2 MB [4][64][4096] bf16

    qk_kernel<<<BATCH * (NSP / 64), 256, 0, stream>>>(x, Wm, bias, qkT, xbf);

    const size_t HEAD = 2097152 + 2097152;
    const size_t needBig = HEAD + (size_t)512 * 16384 * 2 + (size_t)512 * 256 * 4;  // ~21 MB
    if (ws_size >= needBig) {
        __bf16* Opart = (__bf16*)(ws + HEAD);                           // 16 MB [512][64][256]
        float*  Lpart = (float*)(ws + HEAD + (size_t)512 * 16384 * 2);  // 512 KB
        attn_kernel<8, 8><<<BATCH * 16 * 8, 256, 0, stream>>>(xbf, qkT, Opart, Lpart);
        reduce_kernel<8><<<512, 256, 0, stream>>>(Opart, Lpart, out);
    } else {
        __bf16* Opart = (__bf16*)(ws + HEAD);                           // 8 MB [256][64][256]
        float*  Lpart = (float*)(ws + HEAD + (size_t)256 * 16384 * 2);  // 256 KB
        attn_kernel<4, 16><<<BATCH * 16 * 4, 256, 0, stream>>>(xbf, qkT, Opart, Lpart);
        reduce_kernel<4><<<512, 256, 0, stream>>>(Opart, Lpart, out);
    }
}

// Round 4
// 96.327 us; speedup vs baseline: 1.0650x; 1.0212x over previous
//
#include <hip/hip_runtime.h>
#include <hip/hip_bf16.h>

// Problem constants (fixed by reference): B=4, C=64, H=W=64, N=4096
#define BATCH 4
#define NSP   4096

// (1/64)*sqrt(log2 e): both Q and K carry this, so S^T = score*log2e/4096 and
// softmax uses raw v_exp_f32 (2^x) with no per-element multiply.
#define QKSCALE 0.0187675376f

typedef __bf16 bf16x8v __attribute__((ext_vector_type(8)));
typedef __bf16 bf16x4v __attribute__((ext_vector_type(4)));
typedef float  floatx4 __attribute__((ext_vector_type(4)));
typedef float  floatx16 __attribute__((ext_vector_type(16)));
typedef unsigned uivec2 __attribute__((ext_vector_type(2)));

static __device__ __forceinline__ float fast_exp2(float x) {
#if __has_builtin(__builtin_amdgcn_exp2f)
    return __builtin_amdgcn_exp2f(x);
#else
    return exp2f(x);
#endif
}

// pack two f32 -> one dword of 2 bf16 (compiler emits v_cvt_pk_bf16_f32)
static __device__ __forceinline__ unsigned pkbf(float a, float b) {
    union { __bf16 h[2]; unsigned u; } x;
    x.h[0] = (__bf16)a; x.h[1] = (__bf16)b;
    return x.u;
}

// v_permlane32_swap_b32: a'[32:63] <- b[0:31], b'[0:31] <- a[32:63].
// Converts S^T D-layout (4-row groups per half) into PV B-layout (8-row
// groups per half). Verified on HW in R2/R3 (bit-identical absmax).
static __device__ __forceinline__ void plswap(unsigned &a, unsigned &b) {
#if __has_builtin(__builtin_amdgcn_permlane32_swap)
    uivec2 r = __builtin_amdgcn_permlane32_swap(a, b, false, false);
    a = r[0]; b = r[1];
#else
    asm("v_permlane32_swap_b32 %0, %1" : "+v"(a), "+v"(b));
#endif
}

// ---------------------------------------------------------------------------
// Kernel 1: qkT[b][n][o] = bf16( (sum_c W[o][c]*x[b][c][n] + bias[o]) * s ),
// s = QKSCALE (exp2 folding). Also emits xbf = bf16(x) so the attention
// kernel's V staging is a pure uint4 copy. (Unchanged, verified.)
// ---------------------------------------------------------------------------
__global__ __launch_bounds__(256) void qk_kernel(const float* __restrict__ x,
                                                 const float* __restrict__ Wm,
                                                 const float* __restrict__ bias,
                                                 __bf16* __restrict__ qkT,
                                                 __bf16* __restrict__ xbf) {
    __shared__ __align__(16) __bf16 xT[64 * 72];   // [n][c]; reused as [n][o] out buf

    const int t  = threadIdx.x;
    const int b  = blockIdx.x >> 6;
    const int n0 = (blockIdx.x & 63) << 6;

    // stage x^T tile, pre-scaled, coalesced float4 reads; also write bf16 V copy
#pragma unroll
    for (int p = 0; p < 4; ++p) {
        const int c  = p * 16 + (t >> 4);
        const int n4 = (t & 15) * 4;
        const float4 v = *(const float4*)(x + (size_t)(b * 64 + c) * 4096 + n0 + n4);
        xT[(n4 + 0) * 72 + c] = (__bf16)(v.x * QKSCALE);
        xT[(n4 + 1) * 72 + c] = (__bf16)(v.y * QKSCALE);
        xT[(n4 + 2) * 72 + c] = (__bf16)(v.z * QKSCALE);
        xT[(n4 + 3) * 72 + c] = (__bf16)(v.w * QKSCALE);
        bf16x4v xv;
        xv[0] = (__bf16)v.x; xv[1] = (__bf16)v.y; xv[2] = (__bf16)v.z; xv[3] = (__bf16)v.w;
        *(bf16x4v*)(xbf + (size_t)(b * 64 + c) * 4096 + n0 + n4) = xv;
    }
    __syncthreads();

    const int w = t >> 6, lane = t & 63, quad = lane >> 4, l16 = lane & 15;
    // A-frags: A[n=l16][c=quad*8+j], wave w owns n-rows w*16..+15
    const bf16x8v a0 = *(const bf16x8v*)(xT + (w * 16 + l16) * 72 + quad * 8);
    const bf16x8v a1 = *(const bf16x8v*)(xT + (w * 16 + l16) * 72 + 32 + quad * 8);

    floatx4 acc[4];
#pragma unroll
    for (int ot = 0; ot < 4; ++ot) {
        // B-frags straight from global W (fp32 -> bf16): B[k=c][n=o], o=ot*16+l16
        const float* wr = Wm + (ot * 16 + l16) * 64;
        float4 wa = *(const float4*)(wr + quad * 8);
        float4 wb = *(const float4*)(wr + quad * 8 + 4);
        float4 wc = *(const float4*)(wr + 32 + quad * 8);
        float4 wd = *(const float4*)(wr + 32 + quad * 8 + 4);
        bf16x8v b0, b1;
        b0[0]=(__bf16)wa.x; b0[1]=(__bf16)wa.y; b0[2]=(__bf16)wa.z; b0[3]=(__bf16)wa.w;
        b0[4]=(__bf16)wb.x; b0[5]=(__bf16)wb.y; b0[6]=(__bf16)wb.z; b0[7]=(__bf16)wb.w;
        b1[0]=(__bf16)wc.x; b1[1]=(__bf16)wc.y; b1[2]=(__bf16)wc.z; b1[3]=(__bf16)wc.w;
        b1[4]=(__bf16)wd.x; b1[5]=(__bf16)wd.y; b1[6]=(__bf16)wd.z; b1[7]=(__bf16)wd.w;
        acc[ot] = floatx4{0.f, 0.f, 0.f, 0.f};
        acc[ot] = __builtin_amdgcn_mfma_f32_16x16x32_bf16(a0, b0, acc[ot], 0, 0, 0);
        acc[ot] = __builtin_amdgcn_mfma_f32_16x16x32_bf16(a1, b1, acc[ot], 0, 0, 0);
    }
    __syncthreads();   // all xT frag reads done before reuse as [n][o]

    // D: row(quad*4+r)=n_local within wave's 16-n, col(l16)=o_local
#pragma unroll
    for (int ot = 0; ot < 4; ++ot) {
        const float bo = bias[ot * 16 + l16] * QKSCALE;
#pragma unroll
        for (int r = 0; r < 4; ++r)
            xT[(w * 16 + quad * 4 + r) * 72 + ot * 16 + l16] = (__bf16)(acc[ot][r] + bo);
    }
    __syncthreads();

    const int n = t >> 2, seg = t & 3;
    __bf16* dst = qkT + (size_t)(b * 4096 + n0 + n) * 64 + seg * 16;
    *(bf16x8v*)dst       = *(const bf16x8v*)(xT + n * 72 + seg * 16);
    *(bf16x8v*)(dst + 8) = *(const bf16x8v*)(xT + n * 72 + seg * 16 + 8);
}

// ---------------------------------------------------------------------------
// Kernel 2: flash-style attention, 32x32 MFMA. R4 change vs R3: OCCUPANCY.
// R3 (wave=64q, ~176 VGPR) capped at 2 waves/SIMD and measured latency-bound
// (16x16->32x32 MFMA halving moved nothing). Now: 512-thr blocks, 8 waves,
// each wave owns 32 q -> per-wave state halves (oacc 32, qf 16) and
// __launch_bounds__(512,4) pins VGPR<=128 -> 16 waves/CU = 4 waves/SIMD.
// All MFMA layouts / XOR swizzle / cvt_pk+permlane32 paths are R3-verified
// and unchanged; only the q-ownership and staging split differ.
// LDS: K dbuf 16KB + V dbuf 16KB = 32KB; epilogue alias [64][260] f32 ->
// 65KB/block, 2 blocks/CU (= grid limit).
// ---------------------------------------------------------------------------
template<int SPLIT, int ITERS>
__global__ __launch_bounds__(512, 4) void attn_kernel(const __bf16* __restrict__ xbf,
                                                      const __bf16* __restrict__ qkT,
                                                      __bf16* __restrict__ Opart,
                                                      float* __restrict__ Lpart) {
    __shared__ __align__(16) char smem[66560];
    __bf16* Klds = (__bf16*)smem;                 // [2][64 m][64 c] swizzled
    __bf16* Vlds = (__bf16*)(smem + 16384);       // [2][64 c][64 m] swizzled
    float*  Olds = (float*)smem;                  // epilogue alias: [64 c][260 q]

    const int t   = threadIdx.x;
    const int blk = blockIdx.x;
    const int xcd = blk & 7;                      // XCD round-robin
    const int b   = xcd >> 1;                     // each b pinned to 2 XCDs
    const int sub = ((blk >> 3) << 1) | (xcd & 1);
    const int qt  = sub / SPLIT;
    const int s   = sub % SPLIT;
    const int n0  = qt << 8;
    const int pblk = (b * 16 + qt) * SPLIT + s;

    const int w = t >> 6, lane = t & 63, l31 = lane & 31, hi = lane >> 5;

    const __bf16* kgl = qkT + (size_t)b * 4096 * 64;   // [n][c] bf16
    const __bf16* vgl = xbf + (size_t)b * 64 * 4096;   // [c][n] bf16

    // Q B-frags from global: B[k = kb*16 + hi*8 + j][q = w*32 + l31]
    bf16x8v qf[4];
    {
        const __bf16* qrow = kgl + (size_t)(n0 + w * 32 + l31) * 64;
#pragma unroll
        for (int kb = 0; kb < 4; ++kb)
            qf[kb] = *(const bf16x8v*)(qrow + kb * 16 + hi * 8);
    }

    // oacc[ct]: 32x32 D tiles: col=q=l31, row c = ct*32+(r&3)+8*(r>>2)+4*hi
    floatx16 oacc[2] = {};
    float rs = 0.f;

    // staging: 1 K-granule + 1 V-granule per thread (16B each), XOR slot
    const int srow = t >> 3;                  // 0..63
    const int scol = t & 7;
    const int slot = ((scol ^ (srow & 7)) * 8);
    uint4 kst, vst;
    auto stage_load = [&](int m0) {
        kst = *(const uint4*)(kgl + (size_t)(m0 + srow) * 64 + scol * 8);
        vst = *(const uint4*)(vgl + (size_t)srow * 4096 + m0 + scol * 8);
    };
    auto stage_write = [&](int buf) {
        *(uint4*)(Klds + buf * 4096 + srow * 64 + slot) = kst;
        *(uint4*)(Vlds + buf * 4096 + srow * 64 + slot) = vst;
    };

    const int mbase = s * (64 * ITERS);
    stage_load(mbase);
    stage_write(0);
    int cur = 0;

    for (int it = 0; it < ITERS; ++it) {
        if (it + 1 < ITERS) stage_load(mbase + ((it + 1) << 6));  // prefetch -> regs
        __syncthreads();                                          // cur buffers visible
        const __bf16* Kc = Klds + cur * 4096;
        const __bf16* Vc = Vlds + cur * 4096;

        __builtin_amdgcn_s_setprio(1);
#pragma unroll
        for (int mt = 0; mt < 2; ++mt) {
            // K A-frags from LDS: A[m = mt*32 + l31][c = kb*16 + hi*8 + j]
            bf16x8v kf[4];
#pragma unroll
            for (int kb = 0; kb < 4; ++kb)
                kf[kb] = *(const bf16x8v*)(Kc + (mt * 32 + l31) * 64 +
                                           (((kb * 2 + hi) ^ (l31 & 7)) * 8));

            // V A-frags: A[c = ct*32 + l31][m'= mt*32 + ks*16 + hi*8 + j]
            bf16x8v vf[2][2];
#pragma unroll
            for (int ct = 0; ct < 2; ++ct)
#pragma unroll
                for (int ks = 0; ks < 2; ++ks)
                    vf[ct][ks] = *(const bf16x8v*)(Vc + (ct * 32 + l31) * 64 +
                                                   (((mt * 4 + ks * 2 + hi) ^ (l31 & 7)) * 8));

            // S^T = K.Q^T (one 32x32 tile per wave)
            floatx16 acc = {};
#pragma unroll
            for (int kb = 0; kb < 4; ++kb)
                acc = __builtin_amdgcn_mfma_f32_32x32x16_bf16(kf[kb], qf[kb], acc, 0, 0, 0);

            // softmax numerator: p = 2^sT (rows m' = (r&3)+8*(r>>2)+4*hi)
            float p[16];
            float sum = 0.f;
#pragma unroll
            for (int i = 0; i < 16; ++i) { p[i] = fast_exp2(acc[i]); sum += p[i]; }
            rs += sum;

            // pack row-pairs, swap halves -> PV B-frags (k = hi*8 + j)
            unsigned wd0 = pkbf(p[0],  p[1]),  wd1 = pkbf(p[2],  p[3]);
            unsigned wd2 = pkbf(p[4],  p[5]),  wd3 = pkbf(p[6],  p[7]);
            unsigned wd4 = pkbf(p[8],  p[9]),  wd5 = pkbf(p[10], p[11]);
            unsigned wd6 = pkbf(p[12], p[13]), wd7 = pkbf(p[14], p[15]);
            plswap(wd0, wd2);   // wd0 = word0 (k 0,1 | 8,9), wd2 = word2
            plswap(wd1, wd3);   // wd1 = word1,               wd3 = word3
            plswap(wd4, wd6);   // ks=1 block (m'+16)
            plswap(wd5, wd7);
            union { unsigned u[4]; bf16x8v v; } pb0, pb1;
            pb0.u[0] = wd0; pb0.u[1] = wd1; pb0.u[2] = wd2; pb0.u[3] = wd3;
            pb1.u[0] = wd4; pb1.u[1] = wd5; pb1.u[2] = wd6; pb1.u[3] = wd7;

            // O[c][q] += V[c][m'] * P[m'][q]
#pragma unroll
            for (int ct = 0; ct < 2; ++ct) {
                oacc[ct] = __builtin_amdgcn_mfma_f32_32x32x16_bf16(vf[ct][0], pb0.v, oacc[ct], 0, 0, 0);
                oacc[ct] = __builtin_amdgcn_mfma_f32_32x32x16_bf16(vf[ct][1], pb1.v, oacc[ct], 0, 0, 0);
            }
        }
        __builtin_amdgcn_s_setprio(0);

        if (it + 1 < ITERS) stage_write(cur ^ 1);  // vmcnt wait lands here (hidden)
        cur ^= 1;
    }

    // row-sums: each (q, hi) holds a half-sum; combine across halves
    {
        float v = rs + __shfl_xor(rs, 32, 64);
        if (lane < 32)
            Lpart[(size_t)pblk * 256 + w * 32 + l31] = v;
    }

    __syncthreads();   // all K/V LDS reads done before reuse as Olds

    // transpose via LDS: Olds[c][q], then packed bf16 stores
#pragma unroll
    for (int ct = 0; ct < 2; ++ct)
#pragma unroll
        for (int r = 0; r < 16; ++r) {
            const int c = ct * 32 + (r & 3) + 8 * (r >> 2) + 4 * hi;
            Olds[c * 260 + w * 32 + l31] = oacc[ct][r];
        }
    __syncthreads();

    const int c = t >> 3, qs = (t & 7) * 32;
#pragma unroll
    for (int i = 0; i < 4; ++i) {
        floatx4 v0 = *(const floatx4*)(Olds + c * 260 + qs + i * 8);
        floatx4 v1 = *(const floatx4*)(Olds + c * 260 + qs + i * 8 + 4);
        bf16x8v pk;
        pk[0]=(__bf16)v0[0]; pk[1]=(__bf16)v0[1]; pk[2]=(__bf16)v0[2]; pk[3]=(__bf16)v0[3];
        pk[4]=(__bf16)v1[0]; pk[5]=(__bf16)v1[1]; pk[6]=(__bf16)v1[2]; pk[7]=(__bf16)v1[3];
        *(bf16x8v*)(Opart + (size_t)pblk * 16384 + c * 256 + qs + i * 8) = pk;
    }
}

// ---------------------------------------------------------------------------
// Kernel 3: combine SPLIT m-chunk partials, normalize, store fp32 output.
// 512 blocks x 256 thr; 16B Opart loads, 8-deep MLP. (Unchanged, verified.)
// ---------------------------------------------------------------------------
template<int SPLIT>
__global__ __launch_bounds__(256) void reduce_kernel(const __bf16* __restrict__ Opart,
                                                     const float* __restrict__ Lpart,
                                                     float* __restrict__ out) {
    const int blk = blockIdx.x;            // bq(64) x cq(8)
    const int bq = blk >> 3, cq = blk & 7;
    const int b = bq >> 4, qt = bq & 15;
    const int t = threadIdx.x;
    const int c  = cq * 8 + (t >> 5);      // channel
    const int q8 = (t & 31) * 8;           // q offset (8 per thread)

    float l[8] = {0.f,0.f,0.f,0.f,0.f,0.f,0.f,0.f};
#pragma unroll
    for (int s = 0; s < SPLIT; ++s) {
        const float* lp = Lpart + ((size_t)bq * SPLIT + s) * 256 + q8;
        float4 u = *(const float4*)lp;
        float4 v = *(const float4*)(lp + 4);
        l[0]+=u.x; l[1]+=u.y; l[2]+=u.z; l[3]+=u.w;
        l[4]+=v.x; l[5]+=v.y; l[6]+=v.z; l[7]+=v.w;
    }
    float a[8] = {0.f,0.f,0.f,0.f,0.f,0.f,0.f,0.f};
#pragma unroll
    for (int s = 0; s < SPLIT; ++s) {
        bf16x8v v = *(const bf16x8v*)(Opart + ((size_t)bq * SPLIT + s) * 16384 + c * 256 + q8);
#pragma unroll
        for (int k = 0; k < 8; ++k) a[k] += (float)v[k];
    }
    float* op = out + (size_t)(b * 64 + c) * 4096 + qt * 256 + q8;
    float4 o0, o1;
    o0.x = a[0]/l[0]; o0.y = a[1]/l[1]; o0.z = a[2]/l[2]; o0.w = a[3]/l[3];
    o1.x = a[4]/l[4]; o1.y = a[5]/l[5]; o1.z = a[6]/l[6]; o1.w = a[7]/l[7];
    *(float4*)op       = o0;
    *(float4*)(op + 4) = o1;
}

// ---------------------------------------------------------------------------
extern "C" void kernel_launch(void* const* d_in, const int* in_sizes, int n_in,
                              void* d_out, int out_size, void* d_ws, size_t ws_size,
                              hipStream_t stream) {
    const float* x    = (const float*)d_in[0];   // [4][64][4096]
    const float* Wm   = (const float*)d_in[1];   // [64][64]
    const float* bias = (const float*)d_in[2];   // [64]
    float* out = (float*)d_out;                  // [4][64][4096]

    char* ws = (char*)d_ws;
    __bf16* qkT = (__bf16*)ws;                   // 2 MB [4][4096][64] bf16
    __bf16* xbf = (__bf16*)(ws + 2097152);       // 2 MB [4][64][4096] bf16

    qk_kernel<<<BATCH * (NSP / 64), 256, 0, stream>>>(x, Wm, bias, qkT, xbf);

    const size_t HEAD = 2097152 + 2097152;
    const size_t needBig = HEAD + (size_t)512 * 16384 * 2 + (size_t)512 * 256 * 4;  // ~21 MB
    if (ws_size >= needBig) {
        __bf16* Opart = (__bf16*)(ws + HEAD);                           // 16 MB [512][64][256]
        float*  Lpart = (float*)(ws + HEAD + (size_t)512 * 16384 * 2);  // 512 KB
        attn_kernel<8, 8><<<BATCH * 16 * 8, 512, 0, stream>>>(xbf, qkT, Opart, Lpart);
        reduce_kernel<8><<<512, 256, 0, stream>>>(Opart, Lpart, out);
    } else {
        __bf16* Opart = (__bf16*)(ws + HEAD);                           // 8 MB [256][64][256]
        float*  Lpart = (float*)(ws + HEAD + (size_t)256 * 16384 * 2);  // 256 KB
        attn_kernel<4, 16><<<BATCH * 16 * 4, 512, 0, stream>>>(xbf, qkT, Opart, Lpart);
        reduce_kernel<4><<<512, 256, 0, stream>>>(Opart, Lpart, out);
    }
}